// Round 8
// baseline (286.107 us; speedup 1.0000x reference)
//
#include <hip/hip_runtime.h>

#define N_NODES 50000
#define F_IN 128
#define F_OUT 32
#define E_L 800000
#define NEG_SLOPE 0.2f
#define LN 100000                 // 2 * N_NODES
#define NE 1600000                // 2 * E_L random edges
#define BSH 6                     // 64 nodes per bucket
#define BNODES 64
#define NB 782                    // ceil(50000/64)
#define CAP 2368                  // mean 2048 + ~7 sigma, mult of 64
#define PBLOCKS 256
#define PCHUNK 6250               // PBLOCKS * PCHUNK == NE; 128*6250 == E_L
#define CEDGE 13                  // ceil(PCHUNK / 512)

// ---------------------------------------------------------------------------
// K1: bucket partition, trg-side only. Entry packed (rr:7 | u:17) where
// rr = (l<<6)|(trg&63), u = src + l*N. Per-node degrees counted inline via
// global int atomics on L2-resident 400KB arrays (write-back ~800KB total —
// cheap, unlike float atomics on MB-scale arrays). Phase A keeps the LDS
// hist atomic's return value so phase C does zero LDS atomics. l is
// block-uniform (block 128 starts exactly at E_L). Edge registers use static
// #pragma unroll indexing only (no scratch).
// ---------------------------------------------------------------------------
__global__ __launch_bounds__(512) void partition_kernel(
    const int* __restrict__ e0, const int* __restrict__ e1,
    int* __restrict__ cur_t, int* __restrict__ trgbuf,
    int* __restrict__ cnt_trg, int* __restrict__ cnt_src) {
    __shared__ int hist_t[NB], res_t[NB];
    const int t = threadIdx.x, b = blockIdx.x;
    const int l = (b >= PBLOCKS / 2) ? 1 : 0;
    const int* __restrict__ ei = l ? e1 : e0;
    const int ebase = b * PCHUNK - l * E_L;     // in-layer edge base
    for (int i = t; i < NB; i += 512) hist_t[i] = 0;
    __syncthreads();
    int cu_[CEDGE], ct_[CEDGE], off_[CEDGE];
    #pragma unroll
    for (int j = 0; j < CEDGE; ++j) {
        const int idx = t + j * 512;
        if (idx < PCHUNK) {
            const int e = ebase + idx;
            const int src = ei[e], trg = ei[E_L + e];
            cu_[j] = src; ct_[j] = trg;
            off_[j] = atomicAdd(&hist_t[trg >> BSH], 1);
            atomicAdd(&cnt_trg[l * N_NODES + trg], 1);
            atomicAdd(&cnt_src[l * N_NODES + src], 1);
        } else { ct_[j] = -1; off_[j] = 0; cu_[j] = 0; }
    }
    __syncthreads();
    for (int i = t; i < NB; i += 512)
        res_t[i] = hist_t[i] ? atomicAdd(&cur_t[i], hist_t[i]) : 0;
    __syncthreads();
    #pragma unroll
    for (int j = 0; j < CEDGE; ++j) {
        if (ct_[j] >= 0) {
            const int trg = ct_[j], tb = trg >> BSH;
            const int st = res_t[tb] + off_[j];
            if (st < CAP)
                trgbuf[tb * CAP + st] =
                    (((l << 6) | (trg & 63)) << 17) | (cu_[j] + l * N_NODES);
        }
    }
}

// ---------------------------------------------------------------------------
// K2: proj = (x @ W_proj^T) * outdeg_inv, scaled[(l*N+n)*32+f]. (unchanged;
// Wtt row stride 132 floats = 33 float4-slots (odd) -> conflict-free b128.)
// ---------------------------------------------------------------------------
__global__ __launch_bounds__(256) void proj_kernel(
    const float* __restrict__ x, const float* __restrict__ Wp,
    const int* __restrict__ cnt_trg, float* __restrict__ scaled) {
    __shared__ float Wtt[64][132];   // Wtt[o][k] = Wp[o*128+k]
    __shared__ float xt[8][F_IN];
    const int t = threadIdx.x;
    for (int i = t; i < 64 * F_IN; i += 256) {
        int o = i >> 7, k = i & 127;
        Wtt[o][k] = Wp[i];
    }
    const int lane = t & 63, w = t >> 6;
    const int ntiles = N_NODES / 8;          // 6250, exact
    for (int tile = blockIdx.x; tile < ntiles; tile += gridDim.x) {
        const int base = tile * 8;
        __syncthreads();
        ((float4*)&xt[0][0])[t] = ((const float4*)(x + (size_t)base * F_IN))[t];
        __syncthreads();
        const int n0 = w, n1 = w + 4;
        float acc0 = 0.f, acc1 = 0.f;
        #pragma unroll
        for (int k = 0; k < F_IN; k += 4) {
            float4 wv = *(const float4*)&Wtt[lane][k];
            float4 x0 = *(const float4*)&xt[n0][k];
            float4 x1 = *(const float4*)&xt[n1][k];
            acc0 += wv.x * x0.x + wv.y * x0.y + wv.z * x0.z + wv.w * x0.w;
            acc1 += wv.x * x1.x + wv.y * x1.y + wv.z * x1.z + wv.w * x1.w;
        }
        const int l = lane >> 5, f = lane & 31;
        {
            const int v = l * N_NODES + base + n0;
            const float od = 1.0f / sqrtf((float)(cnt_trg[v] + 2));
            scaled[(size_t)v * F_OUT + f] = acc0 * od;
        }
        {
            const int v = l * N_NODES + base + n1;
            const float od = 1.0f / sqrtf((float)(cnt_trg[v] + 2));
            scaled[(size_t)v * F_OUT + f] = acc1 * od;
        }
    }
}

// ---------------------------------------------------------------------------
// K3: per-bucket LDS counting-sort -> dual-row interleaved register gather
// (one 8-lane group owns BOTH layers of one node: 2x loads in flight, and
// self(l0)=inter(l1) rows shared) -> fold + leaky -> 64->32 GEMM.
// ---------------------------------------------------------------------------
__global__ __launch_bounds__(512) void mega_kernel(
    const int* __restrict__ cur_t, const int* __restrict__ trgbuf,
    const int* __restrict__ cnt_trg, const int* __restrict__ cnt_src,
    const float* __restrict__ scaled, const float* __restrict__ Wm,
    const float* __restrict__ bias, float* __restrict__ out) {
    __shared__ int   colx[CAP];        // 9.25 KB sorted sources
    __shared__ int   rp[128], rdeg[128], cursor[128], sc[128];
    __shared__ float h[BNODES][64];    // 16 KB
    __shared__ float Wt[64][32];       // 8 KB, Wt[k][o] = Wm[o*64+k]
    __shared__ float bs[64];
    const int t = threadIdx.x, b = blockIdx.x;
    for (int i = t; i < 2048; i += 512) Wt[i >> 5][i & 31] = Wm[(i & 31) * 64 + (i >> 5)];
    if (t < 64) bs[t] = bias[t];
    // row degrees -> exclusive scan -> segment starts
    int cnt_r = 0;
    if (t < 128) {
        const int l = t >> 6, n = b * BNODES + (t & 63);
        cnt_r = (n < N_NODES) ? cnt_trg[l * N_NODES + n] : 0;
        rdeg[t] = cnt_r; sc[t] = cnt_r;
    }
    __syncthreads();
    for (int off = 1; off < 128; off <<= 1) {
        int add = (t < 128 && t >= off) ? sc[t - off] : 0;
        __syncthreads();
        if (t < 128) sc[t] += add;
        __syncthreads();
    }
    if (t < 128) { rp[t] = sc[t] - cnt_r; cursor[t] = sc[t] - cnt_r; }
    __syncthreads();
    // counting-sort scatter (LDS int atomics + LDS writes only)
    const int total = min(cur_t[b], CAP);
    for (int i = t; i < total; i += 512) {
        const int p = trgbuf[b * CAP + i];
        const int slot = atomicAdd(&cursor[(p >> 17) & 127], 1);
        colx[slot] = p & 0x1FFFF;
    }
    __syncthreads();
    // dual-row gather: group g = node nl, rows nl (l=0) and nl+64 (l=1)
    const int nl = t >> 3, f = (t & 7) * 4;
    const int n = b * BNODES + nl;
    if (n < N_NODES) {
        const int s0 = rp[nl],      d0 = rdeg[nl];
        const int s1 = rp[nl + 64], d1 = rdeg[nl + 64];
        float4 acc0 = make_float4(0.f, 0.f, 0.f, 0.f);
        float4 acc1 = make_float4(0.f, 0.f, 0.f, 0.f);
        const int m = (d0 > d1) ? d0 : d1;
        #pragma unroll 2
        for (int i = 0; i < m; ++i) {
            if (i < d0) {
                const int u = colx[s0 + i];
                const float4 g = *(const float4*)(scaled + (size_t)u * F_OUT + f);
                acc0.x += g.x; acc0.y += g.y; acc0.z += g.z; acc0.w += g.w;
            }
            if (i < d1) {
                const int u = colx[s1 + i];
                const float4 g = *(const float4*)(scaled + (size_t)u * F_OUT + f);
                acc1.x += g.x; acc1.y += g.y; acc1.z += g.z; acc1.w += g.w;
            }
        }
        // self(l0)=scaled[v], inter(l0)=scaled[vp]; layer1 uses the SAME pair
        const int v = n, vp = N_NODES + n;
        const float4 sv = *(const float4*)(scaled + (size_t)v  * F_OUT + f);
        const float4 pv = *(const float4*)(scaled + (size_t)vp * F_OUT + f);
        const float id0 = rsqrtf((float)(cnt_src[v]  + 2));
        const float id1 = rsqrtf((float)(cnt_src[vp] + 2));
        float4 h0, h1;
        h0.x = (acc0.x + sv.x + pv.x) * id0 + bs[f + 0];
        h0.y = (acc0.y + sv.y + pv.y) * id0 + bs[f + 1];
        h0.z = (acc0.z + sv.z + pv.z) * id0 + bs[f + 2];
        h0.w = (acc0.w + sv.w + pv.w) * id0 + bs[f + 3];
        h1.x = (acc1.x + sv.x + pv.x) * id1 + bs[32 + f + 0];
        h1.y = (acc1.y + sv.y + pv.y) * id1 + bs[32 + f + 1];
        h1.z = (acc1.z + sv.z + pv.z) * id1 + bs[32 + f + 2];
        h1.w = (acc1.w + sv.w + pv.w) * id1 + bs[32 + f + 3];
        h0.x = (h0.x >= 0.f) ? h0.x : NEG_SLOPE * h0.x;
        h0.y = (h0.y >= 0.f) ? h0.y : NEG_SLOPE * h0.y;
        h0.z = (h0.z >= 0.f) ? h0.z : NEG_SLOPE * h0.z;
        h0.w = (h0.w >= 0.f) ? h0.w : NEG_SLOPE * h0.w;
        h1.x = (h1.x >= 0.f) ? h1.x : NEG_SLOPE * h1.x;
        h1.y = (h1.y >= 0.f) ? h1.y : NEG_SLOPE * h1.y;
        h1.z = (h1.z >= 0.f) ? h1.z : NEG_SLOPE * h1.z;
        h1.w = (h1.w >= 0.f) ? h1.w : NEG_SLOPE * h1.w;
        *(float4*)&h[nl][f]      = h0;
        *(float4*)&h[nl][32 + f] = h1;
    }
    __syncthreads();
    // merge GEMM: out[n][o] = sum_k h[n][k] * Wm[o][k]
    for (int i = t; i < BNODES * 32; i += 512) {
        const int nl2 = i >> 5, o = i & 31, n2 = b * BNODES + nl2;
        if (n2 < N_NODES) {
            float acc = 0.f;
            #pragma unroll
            for (int k = 0; k < 64; ++k)
                acc += h[nl2][k] * Wt[k][o];          // h: broadcast; Wt: cf
            out[(size_t)n2 * F_OUT + o] = acc;
        }
    }
}

// ---------------------------------------------------------------------------
extern "C" void kernel_launch(void* const* d_in, const int* in_sizes, int n_in,
                              void* d_out, int out_size, void* d_ws, size_t ws_size,
                              hipStream_t stream) {
    const float* x    = (const float*)d_in[0];
    const int*   e0   = (const int*)d_in[1];
    const int*   e1   = (const int*)d_in[2];
    const float* Wp   = (const float*)d_in[3];
    const float* Wm   = (const float*)d_in[4];
    const float* bias = (const float*)d_in[5];
    float* out = (float*)d_out;

    // workspace (~21.0 MB): scaled | trgbuf | [cur_t | cnt_trg | cnt_src]
    // (the bracketed tail is one contiguous zeroed region)
    float* scaled  = (float*)d_ws;                        // 12.8 MB
    int* trgbuf  = (int*)((char*)d_ws + (size_t)LN * F_OUT * sizeof(float)); // 7.4 MB
    int* cur_t   = trgbuf + (size_t)NB * CAP;             // NB ints
    int* cnt_trg = cur_t + NB;                            // 400 KB
    int* cnt_src = cnt_trg + LN;                          // 400 KB

    hipMemsetAsync(cur_t, 0, (size_t)(NB + 2 * LN) * sizeof(int), stream);

    partition_kernel<<<PBLOCKS, 512, 0, stream>>>(e0, e1, cur_t, trgbuf,
                                                  cnt_trg, cnt_src);
    proj_kernel<<<1024, 256, 0, stream>>>(x, Wp, cnt_trg, scaled);
    mega_kernel<<<NB, 512, 0, stream>>>(cur_t, trgbuf, cnt_trg, cnt_src,
                                        scaled, Wm, bias, out);
}

// Round 10
// 191.042 us; speedup vs baseline: 1.4976x; 1.4976x over previous
//
#include <hip/hip_runtime.h>

#define N_NODES 50000
#define F_IN 128
#define F_OUT 32
#define E_L 800000
#define NEG_SLOPE 0.2f
#define LN 100000                 // 2 * N_NODES
#define NE 1600000                // 2 * E_L random edges
#define BSH 6                     // 64 nodes per bucket
#define BNODES 64
#define NB 782                    // ceil(50000/64)
#define CAP 2368                  // mean 2048 + ~7 sigma, mult of 64
#define PBLOCKS 256
#define PCHUNK 6250               // PBLOCKS * PCHUNK == NE; 128*6250 == E_L
#define CEDGE 13                  // ceil(PCHUNK / 512)

// ---------------------------------------------------------------------------
// K1: bucket partition. NO global atomics (r8 lesson: 3.2M device-scope int
// atomics = ~102MB fabric RMW traffic). trg entry packed (rr:7 | u:17),
// rr=(l<<6)|(trg&63), u=src+l*N; src side 1-byte (l<<6)|(src&63) for degree
// counting in count_kernel. Block-level LDS hist reserves contiguous global
// ranges (256 blocks -> 32B avg trgbuf chunks, lowest measured write-amp).
// Phase A keeps the LDS atomic's return value -> phase C has zero atomics.
// l is block-uniform (block 128 starts exactly at E_L).
// ---------------------------------------------------------------------------
__global__ __launch_bounds__(512) void partition_kernel(
    const int* __restrict__ e0, const int* __restrict__ e1,
    int* __restrict__ cur_t, int* __restrict__ cur_s,
    int* __restrict__ trgbuf, unsigned char* __restrict__ srcbuf) {
    __shared__ int hist_t[NB], hist_s[NB], res_t[NB], res_s[NB];
    const int t = threadIdx.x, b = blockIdx.x;
    const int l = (b >= PBLOCKS / 2) ? 1 : 0;
    const int* __restrict__ ei = l ? e1 : e0;
    const int ebase = b * PCHUNK - l * E_L;     // in-layer edge base
    for (int i = t; i < NB; i += 512) { hist_t[i] = 0; hist_s[i] = 0; }
    __syncthreads();
    int cu_[CEDGE], ct_[CEDGE], ot_[CEDGE], os_[CEDGE];
    #pragma unroll
    for (int j = 0; j < CEDGE; ++j) {
        const int idx = t + j * 512;
        if (idx < PCHUNK) {
            const int e = ebase + idx;
            const int src = ei[e], trg = ei[E_L + e];
            cu_[j] = src; ct_[j] = trg;
            ot_[j] = atomicAdd(&hist_t[trg >> BSH], 1);
            os_[j] = atomicAdd(&hist_s[src >> BSH], 1);
        } else { cu_[j] = 0; ct_[j] = -1; ot_[j] = 0; os_[j] = 0; }
    }
    __syncthreads();
    for (int i = t; i < NB; i += 512) {
        res_t[i] = hist_t[i] ? atomicAdd(&cur_t[i], hist_t[i]) : 0;
        res_s[i] = hist_s[i] ? atomicAdd(&cur_s[i], hist_s[i]) : 0;
    }
    __syncthreads();
    #pragma unroll
    for (int j = 0; j < CEDGE; ++j) {
        if (ct_[j] >= 0) {
            const int src = cu_[j], trg = ct_[j];
            const int st = res_t[trg >> BSH] + ot_[j];
            const int ss = res_s[src >> BSH] + os_[j];
            if (st < CAP)
                trgbuf[(trg >> BSH) * CAP + st] =
                    (((l << 6) | (trg & 63)) << 17) | (src + l * N_NODES);
            if (ss < CAP)
                srcbuf[(src >> BSH) * CAP + ss] =
                    (unsigned char)((l << 6) | (src & 63));
        }
    }
}

// ---------------------------------------------------------------------------
// K2: per-bucket LDS hists -> dense cnt_trg / cnt_src (128 rows per bucket).
// ---------------------------------------------------------------------------
__global__ __launch_bounds__(256) void count_kernel(
    const int* __restrict__ cur_t, const int* __restrict__ cur_s,
    const int* __restrict__ trgbuf, const unsigned char* __restrict__ srcbuf,
    int* __restrict__ cnt_trg, int* __restrict__ cnt_src) {
    __shared__ int ht[128], hs[128];
    const int t = threadIdx.x, b = blockIdx.x;
    if (t < 128) { ht[t] = 0; hs[t] = 0; }
    __syncthreads();
    const int ct = min(cur_t[b], CAP), cs = min(cur_s[b], CAP);
    for (int i = t; i < ct; i += 256)
        atomicAdd(&ht[(trgbuf[b * CAP + i] >> 17) & 127], 1);
    for (int i = t; i < cs; i += 256)
        atomicAdd(&hs[srcbuf[b * CAP + i] & 127], 1);
    __syncthreads();
    if (t < 128) {
        const int l = t >> 6, n = b * BNODES + (t & 63);
        if (n < N_NODES) {
            cnt_trg[l * N_NODES + n] = ht[t];
            cnt_src[l * N_NODES + n] = hs[t];
        }
    }
}

// ---------------------------------------------------------------------------
// K3: proj = (x @ W_proj^T) * outdeg_inv, scaled[(l*N+n)*32+f]. (unchanged;
// Wtt row stride 132 floats = 33 float4-slots (odd) -> conflict-free b128.)
// ---------------------------------------------------------------------------
__global__ __launch_bounds__(256) void proj_kernel(
    const float* __restrict__ x, const float* __restrict__ Wp,
    const int* __restrict__ cnt_trg, float* __restrict__ scaled) {
    __shared__ float Wtt[64][132];   // Wtt[o][k] = Wp[o*128+k]
    __shared__ float xt[8][F_IN];
    const int t = threadIdx.x;
    for (int i = t; i < 64 * F_IN; i += 256) {
        int o = i >> 7, k = i & 127;
        Wtt[o][k] = Wp[i];
    }
    const int lane = t & 63, w = t >> 6;
    const int ntiles = N_NODES / 8;          // 6250, exact
    for (int tile = blockIdx.x; tile < ntiles; tile += gridDim.x) {
        const int base = tile * 8;
        __syncthreads();
        ((float4*)&xt[0][0])[t] = ((const float4*)(x + (size_t)base * F_IN))[t];
        __syncthreads();
        const int n0 = w, n1 = w + 4;
        float acc0 = 0.f, acc1 = 0.f;
        #pragma unroll
        for (int k = 0; k < F_IN; k += 4) {
            float4 wv = *(const float4*)&Wtt[lane][k];
            float4 x0 = *(const float4*)&xt[n0][k];
            float4 x1 = *(const float4*)&xt[n1][k];
            acc0 += wv.x * x0.x + wv.y * x0.y + wv.z * x0.z + wv.w * x0.w;
            acc1 += wv.x * x1.x + wv.y * x1.y + wv.z * x1.z + wv.w * x1.w;
        }
        const int l = lane >> 5, f = lane & 31;
        {
            const int v = l * N_NODES + base + n0;
            const float od = 1.0f / sqrtf((float)(cnt_trg[v] + 2));
            scaled[(size_t)v * F_OUT + f] = acc0 * od;
        }
        {
            const int v = l * N_NODES + base + n1;
            const float od = 1.0f / sqrtf((float)(cnt_trg[v] + 2));
            scaled[(size_t)v * F_OUT + f] = acc1 * od;
        }
    }
}

// ---------------------------------------------------------------------------
// K4: per-bucket LDS counting-sort -> dual-row interleaved register gather
// (one 8-lane group owns BOTH layers of one node: unroll 4 -> ~8 loads in
// flight, self(l0)=inter(l1) rows shared) -> fold + leaky -> 64->32 GEMM.
// ---------------------------------------------------------------------------
__global__ __launch_bounds__(512) void mega_kernel(
    const int* __restrict__ cur_t, const int* __restrict__ trgbuf,
    const int* __restrict__ cnt_trg, const int* __restrict__ cnt_src,
    const float* __restrict__ scaled, const float* __restrict__ Wm,
    const float* __restrict__ bias, float* __restrict__ out) {
    __shared__ int   colx[CAP];        // 9.25 KB sorted sources
    __shared__ int   rp[128], rdeg[128], cursor[128], sc[128];
    __shared__ float h[BNODES][64];    // 16 KB
    __shared__ float Wt[64][32];       // 8 KB, Wt[k][o] = Wm[o*64+k]
    __shared__ float bs[64];
    const int t = threadIdx.x, b = blockIdx.x;
    for (int i = t; i < 2048; i += 512) Wt[i >> 5][i & 31] = Wm[(i & 31) * 64 + (i >> 5)];
    if (t < 64) bs[t] = bias[t];
    // row degrees -> exclusive scan -> segment starts
    int cnt_r = 0;
    if (t < 128) {
        const int l = t >> 6, n = b * BNODES + (t & 63);
        cnt_r = (n < N_NODES) ? cnt_trg[l * N_NODES + n] : 0;
        rdeg[t] = cnt_r; sc[t] = cnt_r;
    }
    __syncthreads();
    for (int off = 1; off < 128; off <<= 1) {
        int add = (t < 128 && t >= off) ? sc[t - off] : 0;
        __syncthreads();
        if (t < 128) sc[t] += add;
        __syncthreads();
    }
    if (t < 128) { rp[t] = sc[t] - cnt_r; cursor[t] = sc[t] - cnt_r; }
    __syncthreads();
    // counting-sort scatter (LDS int atomics + LDS writes only)
    const int total = min(cur_t[b], CAP);
    for (int i = t; i < total; i += 512) {
        const int p = trgbuf[b * CAP + i];
        const int slot = atomicAdd(&cursor[(p >> 17) & 127], 1);
        colx[slot] = p & 0x1FFFF;
    }
    __syncthreads();
    // dual-row gather: group g = node nl, rows nl (l=0) and nl+64 (l=1)
    const int nl = t >> 3, f = (t & 7) * 4;
    const int n = b * BNODES + nl;
    if (n < N_NODES) {
        const int s0 = rp[nl],      d0 = rdeg[nl];
        const int s1 = rp[nl + 64], d1 = rdeg[nl + 64];
        float4 acc0 = make_float4(0.f, 0.f, 0.f, 0.f);
        float4 acc1 = make_float4(0.f, 0.f, 0.f, 0.f);
        const int m = (d0 > d1) ? d0 : d1;
        #pragma unroll 4
        for (int i = 0; i < m; ++i) {
            if (i < d0) {
                const int u = colx[s0 + i];
                const float4 g = *(const float4*)(scaled + (size_t)u * F_OUT + f);
                acc0.x += g.x; acc0.y += g.y; acc0.z += g.z; acc0.w += g.w;
            }
            if (i < d1) {
                const int u = colx[s1 + i];
                const float4 g = *(const float4*)(scaled + (size_t)u * F_OUT + f);
                acc1.x += g.x; acc1.y += g.y; acc1.z += g.z; acc1.w += g.w;
            }
        }
        // self(l0)=scaled[v], inter(l0)=scaled[vp]; layer1 uses the SAME pair
        const int v = n, vp = N_NODES + n;
        const float4 sv = *(const float4*)(scaled + (size_t)v  * F_OUT + f);
        const float4 pv = *(const float4*)(scaled + (size_t)vp * F_OUT + f);
        const float id0 = rsqrtf((float)(cnt_src[v]  + 2));
        const float id1 = rsqrtf((float)(cnt_src[vp] + 2));
        float4 h0, h1;
        h0.x = (acc0.x + sv.x + pv.x) * id0 + bs[f + 0];
        h0.y = (acc0.y + sv.y + pv.y) * id0 + bs[f + 1];
        h0.z = (acc0.z + sv.z + pv.z) * id0 + bs[f + 2];
        h0.w = (acc0.w + sv.w + pv.w) * id0 + bs[f + 3];
        h1.x = (acc1.x + sv.x + pv.x) * id1 + bs[32 + f + 0];
        h1.y = (acc1.y + sv.y + pv.y) * id1 + bs[32 + f + 1];
        h1.z = (acc1.z + sv.z + pv.z) * id1 + bs[32 + f + 2];
        h1.w = (acc1.w + sv.w + pv.w) * id1 + bs[32 + f + 3];
        h0.x = (h0.x >= 0.f) ? h0.x : NEG_SLOPE * h0.x;
        h0.y = (h0.y >= 0.f) ? h0.y : NEG_SLOPE * h0.y;
        h0.z = (h0.z >= 0.f) ? h0.z : NEG_SLOPE * h0.z;
        h0.w = (h0.w >= 0.f) ? h0.w : NEG_SLOPE * h0.w;
        h1.x = (h1.x >= 0.f) ? h1.x : NEG_SLOPE * h1.x;
        h1.y = (h1.y >= 0.f) ? h1.y : NEG_SLOPE * h1.y;
        h1.z = (h1.z >= 0.f) ? h1.z : NEG_SLOPE * h1.z;
        h1.w = (h1.w >= 0.f) ? h1.w : NEG_SLOPE * h1.w;
        *(float4*)&h[nl][f]      = h0;
        *(float4*)&h[nl][32 + f] = h1;
    }
    __syncthreads();
    // merge GEMM: out[n][o] = sum_k h[n][k] * Wm[o][k]
    for (int i = t; i < BNODES * 32; i += 512) {
        const int nl2 = i >> 5, o = i & 31, n2 = b * BNODES + nl2;
        if (n2 < N_NODES) {
            float acc = 0.f;
            #pragma unroll
            for (int k = 0; k < 64; ++k)
                acc += h[nl2][k] * Wt[k][o];          // h: broadcast; Wt: cf
            out[(size_t)n2 * F_OUT + o] = acc;
        }
    }
}

// ---------------------------------------------------------------------------
extern "C" void kernel_launch(void* const* d_in, const int* in_sizes, int n_in,
                              void* d_out, int out_size, void* d_ws, size_t ws_size,
                              hipStream_t stream) {
    const float* x    = (const float*)d_in[0];
    const int*   e0   = (const int*)d_in[1];
    const int*   e1   = (const int*)d_in[2];
    const float* Wp   = (const float*)d_in[3];
    const float* Wm   = (const float*)d_in[4];
    const float* bias = (const float*)d_in[5];
    float* out = (float*)d_out;

    // workspace (~21.0 MB)
    float* scaled = (float*)d_ws;                         // 12.8 MB
    unsigned char* srcbuf = (unsigned char*)d_ws;         // aliases scaled (1.85 MB),
                                                          // dead before proj writes
    int* trgbuf  = (int*)((char*)d_ws + (size_t)LN * F_OUT * sizeof(float)); // 7.4 MB
    int* cur_t   = trgbuf + (size_t)NB * CAP;             // NB ints
    int* cur_s   = cur_t + NB;                            // NB ints
    int* cnt_trg = cur_s + NB;                            // 400 KB
    int* cnt_src = cnt_trg + LN;                          // 400 KB

    hipMemsetAsync(cur_t, 0, 2 * NB * sizeof(int), stream);

    partition_kernel<<<PBLOCKS, 512, 0, stream>>>(e0, e1, cur_t, cur_s,
                                                  trgbuf, srcbuf);
    count_kernel<<<NB, 256, 0, stream>>>(cur_t, cur_s, trgbuf, srcbuf,
                                         cnt_trg, cnt_src);
    proj_kernel<<<1024, 256, 0, stream>>>(x, Wp, cnt_trg, scaled);
    mega_kernel<<<NB, 512, 0, stream>>>(cur_t, trgbuf, cnt_trg, cnt_src,
                                        scaled, Wm, bias, out);
}